// Round 1
// baseline (403.730 us; speedup 1.0000x reference)
//
#include <hip/hip_runtime.h>

#define W_ 320
#define H_ 96
#define B_ 4
#define C_ 256
#define QT 64
#define KC 32
#define NSTEP (C_ / KC)   // 8
#define PITCH 36          // staged bf16 row pitch (72 B: 8B-aligned rows, bank-spread)
#define PITCHC 321        // corr bf16 row pitch
#define CS (H_ * W_)      // channel stride = 30720

typedef __attribute__((ext_vector_type(8))) short short8;
typedef __attribute__((ext_vector_type(4))) float f32x4;

static __device__ __forceinline__ unsigned f2bf(float f) {
  unsigned u = __builtin_bit_cast(unsigned, f);
  return (u + 0x7FFFu + ((u >> 16) & 1u)) >> 16;   // RNE fp32 -> bf16
}
static __device__ __forceinline__ float bf2f(unsigned short h) {
  return __builtin_bit_cast(float, (unsigned)h << 16);
}

union Frag { short8 s; uint2 u[2]; };

__global__ __launch_bounds__(256) void corr_fused(
    const float* __restrict__ fmap1, const float* __restrict__ fmap2,
    const float* __restrict__ cents, float* __restrict__ out)
{
  // staging (27648 B) and corr (41088 B) live at different times -> overlap
  __shared__ __align__(16) unsigned short smem[QT * PITCHC]; // 41088 B
  unsigned short* Ash = smem;                 // [QT][PITCH]
  unsigned short* Bsh = smem + QT * PITCH;    // [W_][PITCH]
  unsigned short* Csh = smem;                 // [QT][PITCHC]

  const int tid  = threadIdx.x;
  const int lane = tid & 63;
  const int wave = tid >> 6;
  const int m    = lane & 15;
  const int quad = lane >> 4;

  const int bid = blockIdx.x;
  const int qt  = bid % 5;
  const int hh  = (bid / 5) % H_;
  const int b   = bid / (5 * H_);
  const int q0  = qt * QT;

  const float* f1p = fmap1 + (size_t)b * C_ * CS + hh * W_ + q0; // + c*CS + q
  const float* f2p = fmap2 + (size_t)b * C_ * CS + hh * W_;      // + c*CS + v

  f32x4 acc[4][5] = {};

  for (int step = 0; step < NSTEP; ++step) {
    const float* f1s = f1p + step * KC * CS;
    const float* f2s = f2p + step * KC * CS;
    __syncthreads();
    // stage A: 64 q x 32 k (8 c-quads), 512 items, 2 per thread
    for (int it = tid; it < QT * 8; it += 256) {
      int q = it & 63, c4 = it >> 6;
      const float* p = f1s + c4 * 4 * CS + q;
      uint2 uv;
      uv.x = f2bf(p[0])      | (f2bf(p[CS])     << 16);
      uv.y = f2bf(p[2 * CS]) | (f2bf(p[3 * CS]) << 16);
      *(uint2*)(Ash + q * PITCH + c4 * 4) = uv;
    }
    // stage B (transposed): 320 v x 32 k, 2560 items, 10 per thread
    for (int it = tid; it < W_ * 8; it += 256) {
      int v = it % W_, c4 = it / W_;
      const float* p = f2s + c4 * 4 * CS + v;
      uint2 uv;
      uv.x = f2bf(p[0])      | (f2bf(p[CS])     << 16);
      uv.y = f2bf(p[2 * CS]) | (f2bf(p[3 * CS]) << 16);
      *(uint2*)(Bsh + v * PITCH + c4 * 4) = uv;
    }
    __syncthreads();

    Frag fa[4], fb[5];
#pragma unroll
    for (int mt = 0; mt < 4; ++mt) {
      const unsigned short* pa = Ash + (mt * 16 + m) * PITCH + quad * 8;
      fa[mt].u[0] = *(const uint2*)pa;
      fa[mt].u[1] = *(const uint2*)(pa + 4);
    }
#pragma unroll
    for (int nt = 0; nt < 5; ++nt) {
      const unsigned short* pb = Bsh + (wave * 80 + nt * 16 + m) * PITCH + quad * 8;
      fb[nt].u[0] = *(const uint2*)pb;
      fb[nt].u[1] = *(const uint2*)(pb + 4);
    }
#pragma unroll
    for (int mt = 0; mt < 4; ++mt)
#pragma unroll
      for (int nt = 0; nt < 5; ++nt)
        acc[mt][nt] = __builtin_amdgcn_mfma_f32_16x16x32_bf16(
            fa[mt].s, fb[nt].s, acc[mt][nt], 0, 0, 0);
  }

  __syncthreads();
  // C/D layout: col = lane&15, row = quad*4 + reg  (guide-verified m89/m91)
#pragma unroll
  for (int mt = 0; mt < 4; ++mt)
#pragma unroll
    for (int nt = 0; nt < 5; ++nt)
#pragma unroll
      for (int r = 0; r < 4; ++r) {
        int row = mt * 16 + quad * 4 + r;
        int col = wave * 80 + nt * 16 + m;
        Csh[row * PITCHC + col] = (unsigned short)f2bf(acc[mt][nt][r] * 0.0625f);
      }
  __syncthreads();

  // phase 2: wave = level (uniform pooling width per wave), lane = query
  const int l   = wave;
  const int q   = lane;
  const int Wl  = W_ >> l;
  const int mul = 1 << l;
  const float invm = 1.0f / (float)mul;
  const float cent = cents[(b * H_ + hh) * W_ + q0 + q];
  const float cl = cent * invm; // exact power-of-2 scaling == iterated /2
  const unsigned short* crow = Csh + q * PITCHC;
  float* op = out + ((size_t)(b * 36 + l * 9) * H_ + hh) * W_ + q0 + q;

#pragma unroll
  for (int j = 0; j < 9; ++j) {
    float x  = cl + (float)(j - 4);
    float x0 = floorf(x);
    float t  = x - x0;
    int i0 = (int)x0;
    float v0 = 0.0f, v1 = 0.0f;
    if (i0 >= 0 && i0 < Wl) {
      float s = 0.0f;
      for (int d = 0; d < mul; ++d) s += bf2f(crow[i0 * mul + d]);
      v0 = s * invm;
    }
    int i1 = i0 + 1;
    if (i1 >= 0 && i1 < Wl) {
      float s = 0.0f;
      for (int d = 0; d < mul; ++d) s += bf2f(crow[i1 * mul + d]);
      v1 = s * invm;
    }
    op[(size_t)j * H_ * W_] = v0 * (1.0f - t) + v1 * t;
  }
}

extern "C" void kernel_launch(void* const* d_in, const int* in_sizes, int n_in,
                              void* d_out, int out_size, void* d_ws, size_t ws_size,
                              hipStream_t stream) {
  const float* fmap1 = (const float*)d_in[0];
  const float* fmap2 = (const float*)d_in[1];
  const float* cents = (const float*)d_in[2];
  float* out = (float*)d_out;
  dim3 grid(B_ * H_ * (W_ / QT)); // 1920 blocks
  corr_fused<<<grid, 256, 0, stream>>>(fmap1, fmap2, cents, out);
}

// Round 2
// 373.916 us; speedup vs baseline: 1.0797x; 1.0797x over previous
//
#include <hip/hip_runtime.h>

#define W_ 320
#define H_ 96
#define B_ 4
#define C_ 256
#define QT 64
#define KC 32
#define NSTEP (C_ / KC)   // 8
#define PITCH 36
#define PITCHC 321
#define CS (H_ * W_)      // 30720
#define FMAP_ELEMS ((size_t)B_ * C_ * H_ * W_)     // 31,457,280
#define WS_NEEDED (2 * FMAP_ELEMS * sizeof(unsigned short))  // 125,829,120 B

typedef __attribute__((ext_vector_type(8))) short short8;
typedef __attribute__((ext_vector_type(4))) float f32x4;

static __device__ __forceinline__ unsigned f2bf(float f) {
  unsigned u = __builtin_bit_cast(unsigned, f);
  return (u + 0x7FFFu + ((u >> 16) & 1u)) >> 16;   // RNE fp32 -> bf16
}
static __device__ __forceinline__ float bf2f(unsigned short h) {
  return __builtin_bit_cast(float, (unsigned)h << 16);
}

union Frag { short8 s; uint4 u; };

// ---- kernel 1: convert + transpose fp32 [B,C,H,W] -> bf16 [B,H,W,C] ----
__global__ __launch_bounds__(256) void convert_t(
    const float* __restrict__ f1, const float* __restrict__ f2,
    unsigned short* __restrict__ t1, unsigned short* __restrict__ t2)
{
  __shared__ unsigned short lds[64 * 68];  // 64c x 64w tile, padded pitch
  int t = blockIdx.x;
  const bool second = (t >= 7680);
  if (second) t -= 7680;
  const int cc = t & 3;              // c-chunk (64 channels)
  const int wc = (t >> 2) % 5;       // w-chunk (64 cols)
  const int hh = (t / 20) % H_;
  const int b  = t / (20 * H_);
  const float* src = (second ? f2 : f1)
      + ((size_t)(b * C_ + cc * 64) * H_ + hh) * W_ + wc * 64;
  unsigned short* dst = (second ? t2 : t1)
      + ((size_t)(b * H_ + hh) * W_ + wc * 64) * C_ + cc * 64;

  const int tid = threadIdx.x;
#pragma unroll
  for (int rep = 0; rep < 4; ++rep) {
    int c  = rep * 16 + (tid >> 4);
    int w4 = (tid & 15) * 4;
    float4 v = *(const float4*)(src + (size_t)c * CS + w4);
    uint2 uv;
    uv.x = f2bf(v.x) | (f2bf(v.y) << 16);
    uv.y = f2bf(v.z) | (f2bf(v.w) << 16);
    *(uint2*)&lds[c * 68 + w4] = uv;
  }
  __syncthreads();
#pragma unroll
  for (int rep = 0; rep < 2; ++rep) {
    int idx = rep * 256 + tid;
    int w  = idx >> 3;           // 0..63
    int cp = (idx & 7) * 8;      // 0..56
    unsigned s0 = lds[(cp + 0) * 68 + w], s1 = lds[(cp + 1) * 68 + w];
    unsigned s2 = lds[(cp + 2) * 68 + w], s3 = lds[(cp + 3) * 68 + w];
    unsigned s4 = lds[(cp + 4) * 68 + w], s5 = lds[(cp + 5) * 68 + w];
    unsigned s6 = lds[(cp + 6) * 68 + w], s7 = lds[(cp + 7) * 68 + w];
    uint4 o;
    o.x = s0 | (s1 << 16); o.y = s2 | (s3 << 16);
    o.z = s4 | (s5 << 16); o.w = s6 | (s7 << 16);
    *(uint4*)(dst + (size_t)w * C_ + cp) = o;
  }
}

// ---- kernel 2: barrier-free MFMA GEMM from transposed bf16 + sampling ----
__global__ __launch_bounds__(256, 3) void corr_mfma(
    const unsigned short* __restrict__ t1, const unsigned short* __restrict__ t2,
    const float* __restrict__ cents, float* __restrict__ out)
{
  __shared__ __align__(16) unsigned short Csh[QT * PITCHC]; // 41088 B

  const int tid  = threadIdx.x;
  const int lane = tid & 63;
  const int wave = tid >> 6;
  const int m    = lane & 15;
  const int quad = lane >> 4;

  const int bid = blockIdx.x;
  const int qt  = bid % 5;
  const int hh  = (bid / 5) % H_;
  const int b   = bid / (5 * H_);
  const int q0  = qt * QT;

  const unsigned short* Arow = t1 + ((size_t)(b * H_ + hh) * W_ + q0) * C_;
  const unsigned short* Brow = t2 + ((size_t)(b * H_ + hh) * W_) * C_;

  f32x4 acc[4][5] = {};

#pragma unroll 1
  for (int step = 0; step < NSTEP; ++step) {
    Frag fa[4], fb[5];
    const unsigned short* ab = Arow + (size_t)m * C_ + step * KC + quad * 8;
#pragma unroll
    for (int mt = 0; mt < 4; ++mt)
      fa[mt].u = *(const uint4*)(ab + (size_t)mt * 16 * C_);
    const unsigned short* bb = Brow + (size_t)(wave * 80 + m) * C_ + step * KC + quad * 8;
#pragma unroll
    for (int nt = 0; nt < 5; ++nt)
      fb[nt].u = *(const uint4*)(bb + (size_t)nt * 16 * C_);
#pragma unroll
    for (int mt = 0; mt < 4; ++mt)
#pragma unroll
      for (int nt = 0; nt < 5; ++nt)
        acc[mt][nt] = __builtin_amdgcn_mfma_f32_16x16x32_bf16(
            fa[mt].s, fb[nt].s, acc[mt][nt], 0, 0, 0);
  }

  // C/D layout: col = lane&15, row = quad*4 + reg
#pragma unroll
  for (int mt = 0; mt < 4; ++mt)
#pragma unroll
    for (int nt = 0; nt < 5; ++nt)
#pragma unroll
      for (int r = 0; r < 4; ++r) {
        int row = mt * 16 + quad * 4 + r;
        int col = wave * 80 + nt * 16 + m;
        Csh[row * PITCHC + col] = (unsigned short)f2bf(acc[mt][nt][r] * 0.0625f);
      }
  __syncthreads();

  // phase 2: wave = level, lane = query
  const int l   = wave;
  const int q   = lane;
  const int Wl  = W_ >> l;
  const int mul = 1 << l;
  const float invm = 1.0f / (float)mul;
  const float cent = cents[(b * H_ + hh) * W_ + q0 + q];
  const float cl = cent * invm;
  const unsigned short* crow = Csh + q * PITCHC;
  float* op = out + ((size_t)(b * 36 + l * 9) * H_ + hh) * W_ + q0 + q;

#pragma unroll
  for (int j = 0; j < 9; ++j) {
    float x  = cl + (float)(j - 4);
    float x0 = floorf(x);
    float t  = x - x0;
    int i0 = (int)x0;
    float v0 = 0.0f, v1 = 0.0f;
    if (i0 >= 0 && i0 < Wl) {
      float s = 0.0f;
      for (int d = 0; d < mul; ++d) s += bf2f(crow[i0 * mul + d]);
      v0 = s * invm;
    }
    int i1 = i0 + 1;
    if (i1 >= 0 && i1 < Wl) {
      float s = 0.0f;
      for (int d = 0; d < mul; ++d) s += bf2f(crow[i1 * mul + d]);
      v1 = s * invm;
    }
    op[(size_t)j * H_ * W_] = v0 * (1.0f - t) + v1 * t;
  }
}

// ---- fallback (round-1 fused kernel) if workspace too small ----
__global__ __launch_bounds__(256) void corr_fused(
    const float* __restrict__ fmap1, const float* __restrict__ fmap2,
    const float* __restrict__ cents, float* __restrict__ out)
{
  __shared__ __align__(16) unsigned short smem[QT * PITCHC];
  unsigned short* Ash = smem;
  unsigned short* Bsh = smem + QT * PITCH;
  unsigned short* Csh = smem;

  const int tid  = threadIdx.x;
  const int lane = tid & 63;
  const int wave = tid >> 6;
  const int m    = lane & 15;
  const int quad = lane >> 4;

  const int bid = blockIdx.x;
  const int qt  = bid % 5;
  const int hh  = (bid / 5) % H_;
  const int b   = bid / (5 * H_);
  const int q0  = qt * QT;

  const float* f1p = fmap1 + (size_t)b * C_ * CS + hh * W_ + q0;
  const float* f2p = fmap2 + (size_t)b * C_ * CS + hh * W_;

  f32x4 acc[4][5] = {};

  for (int step = 0; step < NSTEP; ++step) {
    const float* f1s = f1p + step * KC * CS;
    const float* f2s = f2p + step * KC * CS;
    __syncthreads();
    for (int it = tid; it < QT * 8; it += 256) {
      int q = it & 63, c4 = it >> 6;
      const float* p = f1s + c4 * 4 * CS + q;
      uint2 uv;
      uv.x = f2bf(p[0])      | (f2bf(p[CS])     << 16);
      uv.y = f2bf(p[2 * CS]) | (f2bf(p[3 * CS]) << 16);
      *(uint2*)(Ash + q * PITCH + c4 * 4) = uv;
    }
    for (int it = tid; it < W_ * 8; it += 256) {
      int v = it % W_, c4 = it / W_;
      const float* p = f2s + c4 * 4 * CS + v;
      uint2 uv;
      uv.x = f2bf(p[0])      | (f2bf(p[CS])     << 16);
      uv.y = f2bf(p[2 * CS]) | (f2bf(p[3 * CS]) << 16);
      *(uint2*)(Bsh + v * PITCH + c4 * 4) = uv;
    }
    __syncthreads();

    Frag fa[4], fb[5];
#pragma unroll
    for (int mt = 0; mt < 4; ++mt) {
      const unsigned short* pa = Ash + (mt * 16 + m) * PITCH + quad * 8;
      ((uint2*)&fa[mt])[0] = *(const uint2*)pa;
      ((uint2*)&fa[mt])[1] = *(const uint2*)(pa + 4);
    }
#pragma unroll
    for (int nt = 0; nt < 5; ++nt) {
      const unsigned short* pb = Bsh + (wave * 80 + nt * 16 + m) * PITCH + quad * 8;
      ((uint2*)&fb[nt])[0] = *(const uint2*)pb;
      ((uint2*)&fb[nt])[1] = *(const uint2*)(pb + 4);
    }
#pragma unroll
    for (int mt = 0; mt < 4; ++mt)
#pragma unroll
      for (int nt = 0; nt < 5; ++nt)
        acc[mt][nt] = __builtin_amdgcn_mfma_f32_16x16x32_bf16(
            fa[mt].s, fb[nt].s, acc[mt][nt], 0, 0, 0);
  }

  __syncthreads();
#pragma unroll
  for (int mt = 0; mt < 4; ++mt)
#pragma unroll
    for (int nt = 0; nt < 5; ++nt)
#pragma unroll
      for (int r = 0; r < 4; ++r) {
        int row = mt * 16 + quad * 4 + r;
        int col = wave * 80 + nt * 16 + m;
        Csh[row * PITCHC + col] = (unsigned short)f2bf(acc[mt][nt][r] * 0.0625f);
      }
  __syncthreads();

  const int l   = wave;
  const int q   = lane;
  const int Wl  = W_ >> l;
  const int mul = 1 << l;
  const float invm = 1.0f / (float)mul;
  const float cent = cents[(b * H_ + hh) * W_ + q0 + q];
  const float cl = cent * invm;
  const unsigned short* crow = Csh + q * PITCHC;
  float* op = out + ((size_t)(b * 36 + l * 9) * H_ + hh) * W_ + q0 + q;

#pragma unroll
  for (int j = 0; j < 9; ++j) {
    float x  = cl + (float)(j - 4);
    float x0 = floorf(x);
    float t  = x - x0;
    int i0 = (int)x0;
    float v0 = 0.0f, v1 = 0.0f;
    if (i0 >= 0 && i0 < Wl) {
      float s = 0.0f;
      for (int d = 0; d < mul; ++d) s += bf2f(crow[i0 * mul + d]);
      v0 = s * invm;
    }
    int i1 = i0 + 1;
    if (i1 >= 0 && i1 < Wl) {
      float s = 0.0f;
      for (int d = 0; d < mul; ++d) s += bf2f(crow[i1 * mul + d]);
      v1 = s * invm;
    }
    op[(size_t)j * H_ * W_] = v0 * (1.0f - t) + v1 * t;
  }
}

extern "C" void kernel_launch(void* const* d_in, const int* in_sizes, int n_in,
                              void* d_out, int out_size, void* d_ws, size_t ws_size,
                              hipStream_t stream) {
  const float* fmap1 = (const float*)d_in[0];
  const float* fmap2 = (const float*)d_in[1];
  const float* cents = (const float*)d_in[2];
  float* out = (float*)d_out;

  if (ws_size >= WS_NEEDED) {
    unsigned short* t1 = (unsigned short*)d_ws;
    unsigned short* t2 = t1 + FMAP_ELEMS;
    convert_t<<<dim3(2 * 7680), 256, 0, stream>>>(fmap1, fmap2, t1, t2);
    corr_mfma<<<dim3(B_ * H_ * (W_ / QT)), 256, 0, stream>>>(t1, t2, cents, out);
  } else {
    corr_fused<<<dim3(B_ * H_ * (W_ / QT)), 256, 0, stream>>>(fmap1, fmap2, cents, out);
  }
}

// Round 3
// 336.120 us; speedup vs baseline: 1.2011x; 1.1124x over previous
//
#include <hip/hip_runtime.h>

#define W_ 320
#define H_ 96
#define B_ 4
#define C_ 256
#define KC 32
#define CS (H_ * W_)      // 30720
#define QT 64             // fallback tile
#define PITCH 36          // fallback staging pitch
#define PITCHC 321        // corr bf16 row pitch
#define APITCH 258        // A-tile bf16 row pitch (129 dwords, odd -> bank-spread)
#define FMAP_ELEMS ((size_t)B_ * C_ * H_ * W_)          // 31,457,280
#define WS2_NEEDED (FMAP_ELEMS * sizeof(unsigned short)) // 62,914,560 B
#define WS_FULL (2 * FMAP_ELEMS * sizeof(unsigned short))

typedef __attribute__((ext_vector_type(8))) short short8;
typedef __attribute__((ext_vector_type(4))) float f32x4;

static __device__ __forceinline__ unsigned f2bf(float f) {
  unsigned u = __builtin_bit_cast(unsigned, f);
  return (u + 0x7FFFu + ((u >> 16) & 1u)) >> 16;   // RNE fp32 -> bf16
}
static __device__ __forceinline__ float bf2f(unsigned short h) {
  return __builtin_bit_cast(float, (unsigned)h << 16);
}

union Frag { short8 s; uint4 u; };

// ---- kernel 1: convert + transpose fmap2 fp32 [B,C,H,W] -> bf16 [B,H,W,C] ----
__global__ __launch_bounds__(256) void convert2(
    const float* __restrict__ f2, unsigned short* __restrict__ t2)
{
  __shared__ unsigned short lds[64 * 66];  // 8448 B, 33-dword pitch (odd)
  const int t  = blockIdx.x;
  const int cc = t & 3;
  const int wc = (t >> 2) % 5;
  const int hh = (t / 20) % H_;
  const int b  = t / (20 * H_);
  const float* src = f2 + ((size_t)(b * C_ + cc * 64) * H_ + hh) * W_ + wc * 64;
  unsigned short* dst = t2 + ((size_t)(b * H_ + hh) * W_ + wc * 64) * C_ + cc * 64;

  const int tid = threadIdx.x;
#pragma unroll
  for (int rep = 0; rep < 4; ++rep) {
    int c  = rep * 16 + (tid >> 4);
    int w4 = (tid & 15) * 4;
    float4 v = *(const float4*)(src + (size_t)c * CS + w4);
    unsigned* p = (unsigned*)&lds[c * 66 + w4];   // dword-aligned; banks 2i,2i+1 -> conflict-free
    p[0] = f2bf(v.x) | (f2bf(v.y) << 16);
    p[1] = f2bf(v.z) | (f2bf(v.w) << 16);
  }
  __syncthreads();
#pragma unroll
  for (int rep = 0; rep < 2; ++rep) {
    int idx = rep * 256 + tid;
    int w  = idx >> 3;           // 0..63
    int cp = (idx & 7) * 8;      // 0..56
    unsigned s0 = lds[(cp + 0) * 66 + w], s1 = lds[(cp + 1) * 66 + w];
    unsigned s2 = lds[(cp + 2) * 66 + w], s3 = lds[(cp + 3) * 66 + w];
    unsigned s4 = lds[(cp + 4) * 66 + w], s5 = lds[(cp + 5) * 66 + w];
    unsigned s6 = lds[(cp + 6) * 66 + w], s7 = lds[(cp + 7) * 66 + w];
    uint4 o;
    o.x = s0 | (s1 << 16); o.y = s2 | (s3 << 16);
    o.z = s4 | (s5 << 16); o.w = s6 | (s7 << 16);
    *(uint4*)(dst + (size_t)w * C_ + cp) = o;
  }
}

// ---- kernel 2: A staged in-kernel (fp32), B from t2; pipelined MFMA; sampling ----
__global__ __launch_bounds__(256, 4) void corr_mfma2(
    const float* __restrict__ fmap1, const unsigned short* __restrict__ t2,
    const float* __restrict__ cents, float* __restrict__ out)
{
  __shared__ __align__(16) unsigned short smem[32 * PITCHC]; // 20544 B
  unsigned short* Ash = smem;   // [32 px][APITCH], dead after K-loop
  unsigned short* Csh = smem;   // [32 px][PITCHC], born after K-loop

  const int tid  = threadIdx.x;
  const int lane = tid & 63;
  const int wave = tid >> 6;
  const int m    = lane & 15;
  const int quad = lane >> 4;

  // XCD-grouped decode: the 10 q-tiles sharing one (b,hh) B-row keep the same
  // blockIdx%8 -> same XCD L2 (heuristic only; correctness-independent).
  const int i  = blockIdx.x;
  const int g  = (i & 7) * 48 + (i >> 3) / 10;   // 0..383 == b*H_+hh
  const int qt = (i >> 3) % 10;
  const int b  = g / H_;
  const int hh = g % H_;
  const int q0 = qt * 32;

  // ---- stage A: 32 px x 256 c, fp32 -> bf16, transposed to [w][c] ----
  const float* Abase = fmap1 + ((size_t)b * C_ * H_ + hh) * W_ + q0;
#pragma unroll
  for (int rep = 0; rep < 8; ++rep) {
    int idx = rep * 256 + tid;
    int c  = idx >> 3;           // 0..255
    int w4 = (idx & 7) * 4;      // 0..28
    float4 v = *(const float4*)(Abase + (size_t)c * CS + w4);
    Ash[(w4 + 0) * APITCH + c] = (unsigned short)f2bf(v.x);
    Ash[(w4 + 1) * APITCH + c] = (unsigned short)f2bf(v.y);
    Ash[(w4 + 2) * APITCH + c] = (unsigned short)f2bf(v.z);
    Ash[(w4 + 3) * APITCH + c] = (unsigned short)f2bf(v.w);
  }
  __syncthreads();

  const unsigned short* bb =
      t2 + ((size_t)(b * H_ + hh) * W_ + wave * 80 + m) * C_ + quad * 8;

  f32x4 acc[2][5] = {};
  Frag fa0[2], fa1[2], fb0[5], fb1[5];

  auto loadB = [&](Frag* f, int s) {
#pragma unroll
    for (int nt = 0; nt < 5; ++nt)
      f[nt].u = *(const uint4*)(bb + (size_t)nt * 16 * C_ + s * KC);
  };
  auto loadA = [&](Frag* f, int s) {
#pragma unroll
    for (int mt = 0; mt < 2; ++mt) {
      const unsigned* p =
          (const unsigned*)(Ash + (mt * 16 + m) * APITCH + s * KC + quad * 8);
      f[mt].u.x = p[0]; f[mt].u.y = p[1]; f[mt].u.z = p[2]; f[mt].u.w = p[3];
    }
  };
  auto mstep = [&](Frag* fa, Frag* fb) {
#pragma unroll
    for (int mt = 0; mt < 2; ++mt)
#pragma unroll
      for (int nt = 0; nt < 5; ++nt)
        acc[mt][nt] = __builtin_amdgcn_mfma_f32_16x16x32_bf16(
            fa[mt].s, fb[nt].s, acc[mt][nt], 0, 0, 0);
  };

  loadB(fb0, 0); loadA(fa0, 0);
#pragma unroll
  for (int s = 0; s < 8; s += 2) {
    if (s + 1 < 8) { loadB(fb1, s + 1); loadA(fa1, s + 1); }
    mstep(fa0, fb0);
    if (s + 2 < 8) { loadB(fb0, s + 2); loadA(fa0, s + 2); }
    if (s + 1 < 8) mstep(fa1, fb1);
  }
  __syncthreads();  // A-region dead

  // C/D layout: col = lane&15, row = quad*4 + reg
#pragma unroll
  for (int mt = 0; mt < 2; ++mt)
#pragma unroll
    for (int nt = 0; nt < 5; ++nt)
#pragma unroll
      for (int r = 0; r < 4; ++r)
        Csh[(mt * 16 + quad * 4 + r) * PITCHC + wave * 80 + nt * 16 + m] =
            (unsigned short)f2bf(acc[mt][nt][r] * 0.0625f);
  __syncthreads();

  // sampling: wave = level, lanes 0..31 = query
  if (lane < 32) {
    const int l   = wave;
    const int q   = lane;
    const int Wl  = W_ >> l;
    const int mul = 1 << l;
    const float invm = 1.0f / (float)mul;
    const float cent = cents[(b * H_ + hh) * W_ + q0 + q];
    const float cl = cent * invm;
    const unsigned short* crow = Csh + q * PITCHC;
    float* op = out + ((size_t)(b * 36 + l * 9) * H_ + hh) * W_ + q0 + q;
#pragma unroll
    for (int j = 0; j < 9; ++j) {
      float x  = cl + (float)(j - 4);
      float x0 = floorf(x);
      float t  = x - x0;
      int i0 = (int)x0;
      float v0 = 0.0f, v1 = 0.0f;
      if (i0 >= 0 && i0 < Wl) {
        float ssum = 0.0f;
        for (int d = 0; d < mul; ++d) ssum += bf2f(crow[i0 * mul + d]);
        v0 = ssum * invm;
      }
      int i1 = i0 + 1;
      if (i1 >= 0 && i1 < Wl) {
        float ssum = 0.0f;
        for (int d = 0; d < mul; ++d) ssum += bf2f(crow[i1 * mul + d]);
        v1 = ssum * invm;
      }
      op[(size_t)j * H_ * W_] = v0 * (1.0f - t) + v1 * t;
    }
  }
}

// ---- fallback (round-1 fused kernel) if workspace too small ----
__global__ __launch_bounds__(256) void corr_fused(
    const float* __restrict__ fmap1, const float* __restrict__ fmap2,
    const float* __restrict__ cents, float* __restrict__ out)
{
  __shared__ __align__(16) unsigned short smemf[QT * PITCHC];
  unsigned short* Ash = smemf;
  unsigned short* Bsh = smemf + QT * PITCH;
  unsigned short* Csh = smemf;

  const int tid  = threadIdx.x;
  const int lane = tid & 63;
  const int wave = tid >> 6;
  const int m    = lane & 15;
  const int quad = lane >> 4;

  const int bid = blockIdx.x;
  const int qt  = bid % 5;
  const int hh  = (bid / 5) % H_;
  const int b   = bid / (5 * H_);
  const int q0  = qt * QT;

  const float* f1p = fmap1 + (size_t)b * C_ * CS + hh * W_ + q0;
  const float* f2p = fmap2 + (size_t)b * C_ * CS + hh * W_;

  f32x4 acc[4][5] = {};

  for (int step = 0; step < 8; ++step) {
    const float* f1s = f1p + step * KC * CS;
    const float* f2s = f2p + step * KC * CS;
    __syncthreads();
    for (int it = tid; it < QT * 8; it += 256) {
      int q = it & 63, c4 = it >> 6;
      const float* p = f1s + c4 * 4 * CS + q;
      uint2 uv;
      uv.x = f2bf(p[0])      | (f2bf(p[CS])     << 16);
      uv.y = f2bf(p[2 * CS]) | (f2bf(p[3 * CS]) << 16);
      *(uint2*)(Ash + q * PITCH + c4 * 4) = uv;
    }
    for (int it = tid; it < W_ * 8; it += 256) {
      int v = it % W_, c4 = it / W_;
      const float* p = f2s + c4 * 4 * CS + v;
      uint2 uv;
      uv.x = f2bf(p[0])      | (f2bf(p[CS])     << 16);
      uv.y = f2bf(p[2 * CS]) | (f2bf(p[3 * CS]) << 16);
      *(uint2*)(Bsh + v * PITCH + c4 * 4) = uv;
    }
    __syncthreads();

    Frag fa[4], fb[5];
#pragma unroll
    for (int mt = 0; mt < 4; ++mt) {
      const unsigned short* pa = Ash + (mt * 16 + m) * PITCH + quad * 8;
      ((uint2*)&fa[mt])[0] = *(const uint2*)pa;
      ((uint2*)&fa[mt])[1] = *(const uint2*)(pa + 4);
    }
#pragma unroll
    for (int nt = 0; nt < 5; ++nt) {
      const unsigned short* pb = Bsh + (wave * 80 + nt * 16 + m) * PITCH + quad * 8;
      ((uint2*)&fb[nt])[0] = *(const uint2*)pb;
      ((uint2*)&fb[nt])[1] = *(const uint2*)(pb + 4);
    }
#pragma unroll
    for (int mt = 0; mt < 4; ++mt)
#pragma unroll
      for (int nt = 0; nt < 5; ++nt)
        acc[mt][nt] = __builtin_amdgcn_mfma_f32_16x16x32_bf16(
            fa[mt].s, fb[nt].s, acc[mt][nt], 0, 0, 0);
  }

  __syncthreads();
#pragma unroll
  for (int mt = 0; mt < 4; ++mt)
#pragma unroll
    for (int nt = 0; nt < 5; ++nt)
#pragma unroll
      for (int r = 0; r < 4; ++r)
        Csh[(mt * 16 + quad * 4 + r) * PITCHC + wave * 80 + nt * 16 + m] =
            (unsigned short)f2bf(acc[mt][nt][r] * 0.0625f);
  __syncthreads();

  const int l   = wave;
  const int q   = lane;
  const int Wl  = W_ >> l;
  const int mul = 1 << l;
  const float invm = 1.0f / (float)mul;
  const float cent = cents[(b * H_ + hh) * W_ + q0 + q];
  const float cl = cent * invm;
  const unsigned short* crow = Csh + q * PITCHC;
  float* op = out + ((size_t)(b * 36 + l * 9) * H_ + hh) * W_ + q0 + q;

#pragma unroll
  for (int j = 0; j < 9; ++j) {
    float x  = cl + (float)(j - 4);
    float x0 = floorf(x);
    float t  = x - x0;
    int i0 = (int)x0;
    float v0 = 0.0f, v1 = 0.0f;
    if (i0 >= 0 && i0 < Wl) {
      float ssum = 0.0f;
      for (int d = 0; d < mul; ++d) ssum += bf2f(crow[i0 * mul + d]);
      v0 = ssum * invm;
    }
    int i1 = i0 + 1;
    if (i1 >= 0 && i1 < Wl) {
      float ssum = 0.0f;
      for (int d = 0; d < mul; ++d) ssum += bf2f(crow[i1 * mul + d]);
      v1 = ssum * invm;
    }
    op[(size_t)j * H_ * W_] = v0 * (1.0f - t) + v1 * t;
  }
}

extern "C" void kernel_launch(void* const* d_in, const int* in_sizes, int n_in,
                              void* d_out, int out_size, void* d_ws, size_t ws_size,
                              hipStream_t stream) {
  const float* fmap1 = (const float*)d_in[0];
  const float* fmap2 = (const float*)d_in[1];
  const float* cents = (const float*)d_in[2];
  float* out = (float*)d_out;

  if (ws_size >= WS2_NEEDED) {
    unsigned short* t2 = (unsigned short*)d_ws;
    convert2<<<dim3(20 * H_ * B_), 256, 0, stream>>>(fmap2, t2);     // 7680 blocks
    corr_mfma2<<<dim3(B_ * H_ * 10), 256, 0, stream>>>(fmap1, t2, cents, out); // 3840
  } else {
    corr_fused<<<dim3(B_ * H_ * 5), 256, 0, stream>>>(fmap1, fmap2, cents, out);
  }
}

// Round 4
// 312.625 us; speedup vs baseline: 1.2914x; 1.0752x over previous
//
#include <hip/hip_runtime.h>

#define W_ 320
#define H_ 96
#define B_ 4
#define C_ 256
#define CS (H_ * W_)          // 30720
#define MT_ 160               // M per block (queries)
#define PITCH 34              // shorts per LDS tile row (17 dwords, odd -> bank-spread)
#define PITCHC 321            // corr chunk row pitch (shorts)
#define ABUF (MT_ * PITCH)    // 5440 shorts
#define BBUF (W_ * PITCH)     // 10880 shorts
#define TBUF (ABUF + BBUF)    // 16320 shorts per K-step buffer

typedef __attribute__((ext_vector_type(8))) short short8;
typedef __attribute__((ext_vector_type(4))) float f32x4;

static __device__ __forceinline__ unsigned f2bf(float f) {
  unsigned u = __builtin_bit_cast(unsigned, f);
  return (u + 0x7FFFu + ((u >> 16) & 1u)) >> 16;   // RNE fp32 -> bf16
}
static __device__ __forceinline__ unsigned pk(float a, float b) {
  return f2bf(a) | (f2bf(b) << 16);
}
static __device__ __forceinline__ float bf2f(unsigned short h) {
  return __builtin_bit_cast(float, (unsigned)h << 16);
}

union Frag { short8 s; uint4 u; };

// One block = one (b,hh, half-row): M=160 queries x N=320 cols x K=256 channels.
// fp32 read-direct, bf16 LDS tiles, double-buffered, register ping-pong prefetch.
__global__ __launch_bounds__(512, 2) void corr_row(
    const float* __restrict__ fmap1, const float* __restrict__ fmap2,
    const float* __restrict__ cents, float* __restrict__ out)
{
  __shared__ __align__(16) unsigned short smem[2 * TBUF];   // 65280 B
  unsigned short* Csh = smem;                               // epilogue chunk: 80*321 = 25680 shorts

  const int tid  = threadIdx.x;
  const int lane = tid & 63;
  const int wv   = tid >> 6;      // 0..7
  const int mw   = wv >> 2;       // 0..1  (M half: 80 rows)
  const int nw   = wv & 3;        // 0..3  (N quarter: 80 cols)
  const int m    = lane & 15;
  const int quad = lane >> 4;

  // XCD-paired decode: both halves of row r share blockIdx%8 (L2 locality heuristic)
  const int i    = blockIdx.x;                 // 0..767
  const int r    = ((i >> 4) << 3) | (i & 7);  // 0..383 == b*H_+hh
  const int half = (i >> 3) & 1;
  const int b    = r / H_;
  const int hh   = r % H_;
  const int q0   = half * MT_;

  const float* Abase = fmap1 + ((size_t)b * C_ * H_ + hh) * W_ + q0; // + c*CS + v
  const float* Bbase = fmap2 + ((size_t)b * C_ * H_ + hh) * W_;      // + c*CS + v

  // ---- per-thread staging slots (4): item id = tid + 512*p, 1920 items/step ----
  // A items (it<640):  c2 = it/40, vrow0 = (it%40)*4   (A: 160 rows)
  // B items (it>=640): c2 = ib/80, vrow0 = (ib%80)*4   (B: 320 rows)
  const float* sp[4];
  int dsti[4];        // LDS dword index of (row0, c2) within its tile
  int dstsel[4];      // 0 = A tile, ABUF/2 dword offset for B
  bool act[4];
#pragma unroll
  for (int p = 0; p < 4; ++p) {
    int it = tid + 512 * p;
    act[p] = (it < 1920);
    int c2, v0;
    bool isA = (it < 640);
    if (isA) { c2 = it / 40; v0 = (it % 40) * 4; }
    else     { int ib = it - 640; c2 = ib / 80; v0 = (ib % 80) * 4; }
    if (!act[p]) { c2 = 0; v0 = 0; }
    sp[p]     = (isA ? Abase : Bbase) + (size_t)(2 * c2) * CS + v0;
    dsti[p]   = v0 * 17 + c2;
    dstsel[p] = isA ? 0 : (ABUF / 2);
  }

  f32x4 acc[5][5] = {};
  Frag fa[5];

  float4 g0[4][2], g1[4][2];

  auto issue = [&](int s, float4 (*g)[2]) {
#pragma unroll
    for (int p = 0; p < 4; ++p)
      if (act[p]) {
        const float* q = sp[p] + (size_t)(s * 32) * CS;
        g[p][0] = *(const float4*)q;
        g[p][1] = *(const float4*)(q + CS);
      }
  };
  auto stage = [&](int s, float4 (*g)[2]) {
    unsigned* buf = (unsigned*)(smem + (s & 1) * TBUF);
#pragma unroll
    for (int p = 0; p < 4; ++p)
      if (act[p]) {
        unsigned* d = buf + dstsel[p] + dsti[p];
        d[0]      = pk(g[p][0].x, g[p][1].x);
        d[17]     = pk(g[p][0].y, g[p][1].y);
        d[2 * 17] = pk(g[p][0].z, g[p][1].z);
        d[3 * 17] = pk(g[p][0].w, g[p][1].w);
      }
  };
  auto fragmfma = [&](int s) {
    const unsigned* buf = (const unsigned*)(smem + (s & 1) * TBUF);
#pragma unroll
    for (int mt = 0; mt < 5; ++mt) {
      const unsigned* pa = buf + (mw * 80 + mt * 16 + m) * 17 + quad * 4;
      fa[mt].u.x = pa[0]; fa[mt].u.y = pa[1]; fa[mt].u.z = pa[2]; fa[mt].u.w = pa[3];
    }
#pragma unroll
    for (int nt = 0; nt < 5; ++nt) {
      const unsigned* pb = buf + (ABUF / 2) + (nw * 80 + nt * 16 + m) * 17 + quad * 4;
      Frag fb;
      fb.u.x = pb[0]; fb.u.y = pb[1]; fb.u.z = pb[2]; fb.u.w = pb[3];
#pragma unroll
      for (int mt = 0; mt < 5; ++mt)
        acc[mt][nt] = __builtin_amdgcn_mfma_f32_16x16x32_bf16(
            fa[mt].s, fb.s, acc[mt][nt], 0, 0, 0);
    }
  };

  issue(0, g0);
#pragma unroll
  for (int ss = 0; ss < 4; ++ss) {
    int s = 2 * ss;
    stage(s, g0);
    __syncthreads();
    if (s < 7) issue(s + 1, g1);
    fragmfma(s);

    stage(s + 1, g1);
    __syncthreads();
    if (s + 1 < 7) issue(s + 2, g0);
    fragmfma(s + 1);
  }

  // ---- epilogue: two 80-query chunks through Csh (unions with buffers) ----
#pragma unroll 1
  for (int chunk = 0; chunk < 2; ++chunk) {
    __syncthreads();   // K-loop frag reads done / chunk0 sampling done
    if (mw == chunk) {
      // C/D layout: col = lane&15, row = quad*4 + reg
#pragma unroll
      for (int mt = 0; mt < 5; ++mt)
#pragma unroll
        for (int nt = 0; nt < 5; ++nt)
#pragma unroll
          for (int rr = 0; rr < 4; ++rr)
            Csh[(mt * 16 + quad * 4 + rr) * PITCHC + nw * 80 + nt * 16 + m] =
                (unsigned short)f2bf(acc[mt][nt][rr] * 0.0625f);
    }
    __syncthreads();
    if (tid < 320) {
      const int l = tid / 80;          // level
      const int q = tid % 80;          // query within chunk
      const int qg = q0 + chunk * 80 + q;
      const int Wl  = W_ >> l;
      const int mul = 1 << l;
      const float invm = 1.0f / (float)mul;
      const float cent = cents[(b * H_ + hh) * W_ + qg];
      const float cl = cent * invm;    // exact pow2 scaling == iterated /2
      const unsigned short* crow = Csh + q * PITCHC;
      float* op = out + ((size_t)(b * 36 + l * 9) * H_ + hh) * W_ + qg;
#pragma unroll
      for (int j = 0; j < 9; ++j) {
        float x  = cl + (float)(j - 4);
        float x0 = floorf(x);
        float t  = x - x0;
        int i0 = (int)x0;
        float v0 = 0.0f, v1 = 0.0f;
        if (i0 >= 0 && i0 < Wl) {
          float s2 = 0.0f;
          for (int d = 0; d < mul; ++d) s2 += bf2f(crow[i0 * mul + d]);
          v0 = s2 * invm;
        }
        int i1 = i0 + 1;
        if (i1 >= 0 && i1 < Wl) {
          float s2 = 0.0f;
          for (int d = 0; d < mul; ++d) s2 += bf2f(crow[i1 * mul + d]);
          v1 = s2 * invm;
        }
        op[(size_t)j * H_ * W_] = v0 * (1.0f - t) + v1 * t;
      }
    }
  }
}

extern "C" void kernel_launch(void* const* d_in, const int* in_sizes, int n_in,
                              void* d_out, int out_size, void* d_ws, size_t ws_size,
                              hipStream_t stream) {
  const float* fmap1 = (const float*)d_in[0];
  const float* fmap2 = (const float*)d_in[1];
  const float* cents = (const float*)d_in[2];
  float* out = (float*)d_out;
  corr_row<<<dim3(768), 512, 0, stream>>>(fmap1, fmap2, cents, out);
}